// Round 1
// 312.804 us; speedup vs baseline: 1.0434x; 1.0434x over previous
//
#include <hip/hip_runtime.h>
#include <hip/hip_bf16.h>
#include <math.h>

#define BATCH 64
#define TLEN 512
#define DIM 768
#define NLAB 50

typedef __attribute__((ext_vector_type(8))) short short8;   // 8 bf16 (4 VGPRs)
typedef __attribute__((ext_vector_type(4))) float f32x4;    // MFMA acc

__device__ __forceinline__ unsigned short f2bf(float f) {
    unsigned int u = __float_as_uint(f);
    return (unsigned short)((u + 0x7FFFu + ((u >> 16) & 1u)) >> 16);
}

// ---------------------------------------------------------------------------
// prep: W fp32 [768 x 50] -> Bt bf16 [64 cols][768 k] (transposed, zero-pad)
// ---------------------------------------------------------------------------
__global__ __launch_bounds__(256) void wprep_kernel(const float* __restrict__ W,
                                                    unsigned short* __restrict__ Bt) {
    int idx = blockIdx.x * 256 + threadIdx.x;
    if (idx < 64 * DIM) {
        int c = idx / DIM;
        int k = idx - c * DIM;
        float v = (c < NLAB) ? W[k * NLAB + c] : 0.f;
        Bt[idx] = f2bf(v);
    }
}

// ---------------------------------------------------------------------------
// GEMM: 256 thr / 4 waves, tile 128 rows x 64 cols, K chunks of 32, dbuf LDS.
// ---------------------------------------------------------------------------
#define AST 36
#define BSTC 40

__global__ __launch_bounds__(256, 1) __attribute__((amdgpu_waves_per_eu(1, 1)))
void gemm_kernel(
    const float* __restrict__ A,              // [32768 x 768] fp32
    const unsigned short* __restrict__ Bt,    // [64 x 768] bf16 (W^T, padded)
    const float* __restrict__ bias,
    float* __restrict__ out)                  // [32768 x 50]
{
    __shared__ float As[2][128 * AST];
    __shared__ short Bs[2][64 * BSTC];

    const int tid = threadIdx.x;
    const int wave = tid >> 6;
    const int lane = tid & 63;
    const int m = lane & 15;
    const int q = lane >> 4;
    const int row0 = blockIdx.x * 128;

    const int r0s = tid >> 3, c0s = tid & 7;
    const int bcol = tid >> 2, bkk = (tid & 3) * 8;

    f32x4 acc00 = {0.f,0.f,0.f,0.f}, acc01 = {0.f,0.f,0.f,0.f};
    f32x4 acc02 = {0.f,0.f,0.f,0.f}, acc03 = {0.f,0.f,0.f,0.f};
    f32x4 acc10 = {0.f,0.f,0.f,0.f}, acc11 = {0.f,0.f,0.f,0.f};
    f32x4 acc12 = {0.f,0.f,0.f,0.f}, acc13 = {0.f,0.f,0.f,0.f};

    {
        *(float4*)&As[0][(r0s +  0) * AST + c0s * 4] = *(const float4*)(A + (size_t)(row0 + r0s +  0) * DIM + c0s * 4);
        *(float4*)&As[0][(r0s + 32) * AST + c0s * 4] = *(const float4*)(A + (size_t)(row0 + r0s + 32) * DIM + c0s * 4);
        *(float4*)&As[0][(r0s + 64) * AST + c0s * 4] = *(const float4*)(A + (size_t)(row0 + r0s + 64) * DIM + c0s * 4);
        *(float4*)&As[0][(r0s + 96) * AST + c0s * 4] = *(const float4*)(A + (size_t)(row0 + r0s + 96) * DIM + c0s * 4);
        *(short8*)&Bs[0][bcol * BSTC + bkk] = *(const short8*)(Bt + (size_t)bcol * DIM + bkk);
    }
    __syncthreads();

    int buf = 0;
    for (int ch = 0; ch < DIM / 32; ++ch) {
        const int k0n = (ch + 1) * 32;
        const bool havenext = (ch < DIM / 32 - 1);
        float4 pa0, pa1, pa2, pa3;
        short8 pb;
        if (havenext) {
            pa0 = *(const float4*)(A + (size_t)(row0 + r0s +  0) * DIM + k0n + c0s * 4);
            pa1 = *(const float4*)(A + (size_t)(row0 + r0s + 32) * DIM + k0n + c0s * 4);
            pa2 = *(const float4*)(A + (size_t)(row0 + r0s + 64) * DIM + k0n + c0s * 4);
            pa3 = *(const float4*)(A + (size_t)(row0 + r0s + 96) * DIM + k0n + c0s * 4);
            pb  = *(const short8*)(Bt + (size_t)bcol * DIM + k0n + bkk);
        }

        const short8 bq0 = *(const short8*)&Bs[buf][( 0 + m) * BSTC + q * 8];
        const short8 bq1 = *(const short8*)&Bs[buf][(16 + m) * BSTC + q * 8];
        const short8 bq2 = *(const short8*)&Bs[buf][(32 + m) * BSTC + q * 8];
        const short8 bq3 = *(const short8*)&Bs[buf][(48 + m) * BSTC + q * 8];

        {   // m-tile 0
            const int rr = wave * 32 + m;
            const float4 xa = *(const float4*)&As[buf][rr * AST + q * 8];
            const float4 xb = *(const float4*)&As[buf][rr * AST + q * 8 + 4];
            short8 af;
            af[0] = (short)f2bf(xa.x); af[1] = (short)f2bf(xa.y);
            af[2] = (short)f2bf(xa.z); af[3] = (short)f2bf(xa.w);
            af[4] = (short)f2bf(xb.x); af[5] = (short)f2bf(xb.y);
            af[6] = (short)f2bf(xb.z); af[7] = (short)f2bf(xb.w);
            acc00 = __builtin_amdgcn_mfma_f32_16x16x32_bf16(af, bq0, acc00, 0, 0, 0);
            acc01 = __builtin_amdgcn_mfma_f32_16x16x32_bf16(af, bq1, acc01, 0, 0, 0);
            acc02 = __builtin_amdgcn_mfma_f32_16x16x32_bf16(af, bq2, acc02, 0, 0, 0);
            acc03 = __builtin_amdgcn_mfma_f32_16x16x32_bf16(af, bq3, acc03, 0, 0, 0);
        }
        {   // m-tile 1
            const int rr = wave * 32 + 16 + m;
            const float4 xa = *(const float4*)&As[buf][rr * AST + q * 8];
            const float4 xb = *(const float4*)&As[buf][rr * AST + q * 8 + 4];
            short8 af;
            af[0] = (short)f2bf(xa.x); af[1] = (short)f2bf(xa.y);
            af[2] = (short)f2bf(xa.z); af[3] = (short)f2bf(xa.w);
            af[4] = (short)f2bf(xb.x); af[5] = (short)f2bf(xb.y);
            af[6] = (short)f2bf(xb.z); af[7] = (short)f2bf(xb.w);
            acc10 = __builtin_amdgcn_mfma_f32_16x16x32_bf16(af, bq0, acc10, 0, 0, 0);
            acc11 = __builtin_amdgcn_mfma_f32_16x16x32_bf16(af, bq1, acc11, 0, 0, 0);
            acc12 = __builtin_amdgcn_mfma_f32_16x16x32_bf16(af, bq2, acc12, 0, 0, 0);
            acc13 = __builtin_amdgcn_mfma_f32_16x16x32_bf16(af, bq3, acc13, 0, 0, 0);
        }

        if (havenext) {
            const int nb = buf ^ 1;
            *(float4*)&As[nb][(r0s +  0) * AST + c0s * 4] = pa0;
            *(float4*)&As[nb][(r0s + 32) * AST + c0s * 4] = pa1;
            *(float4*)&As[nb][(r0s + 64) * AST + c0s * 4] = pa2;
            *(float4*)&As[nb][(r0s + 96) * AST + c0s * 4] = pa3;
            *(short8*)&Bs[nb][bcol * BSTC + bkk] = pb;
        }
        __syncthreads();
        buf ^= 1;
    }

#pragma unroll
    for (int mt = 0; mt < 2; ++mt) {
        const f32x4 a0 = mt ? acc10 : acc00;
        const f32x4 a1 = mt ? acc11 : acc01;
        const f32x4 a2 = mt ? acc12 : acc02;
        const f32x4 a3 = mt ? acc13 : acc03;
        const int rb = row0 + wave * 32 + mt * 16 + q * 4;
#pragma unroll
        for (int nt = 0; nt < 4; ++nt) {
            const f32x4 av = (nt == 0) ? a0 : (nt == 1) ? a1 : (nt == 2) ? a2 : a3;
            const int col = nt * 16 + m;
            if (col < NLAB) {
                const float bv = bias[col];
#pragma unroll
                for (int r = 0; r < 4; ++r)
                    out[(size_t)(rb + r) * NLAB + col] = av[r] + bv;
            }
        }
    }
}

// ---------------------------------------------------------------------------
// CRF v9: LDS-free recurrence.
// v8's per-step path was u -> ds_write -> lgkmcnt(0) -> 13x ds_read_b128
// (~120cyc exposed, nothing to hide it at 1 wave/CU) -> 13-deep fma chains.
// v9 broadcasts the 50-wide e-vector with 50x v_readlane_b32 (pure VALU,
// ~4-8 cyc, no lgkm traffic; value feeds v_fmac as the SGPR src directly,
// each consumed immediately so SGPR live ranges are ~1 instr) and splits the
// dot over 8 accumulators (chain 13 -> 7, +3-level combine). Lane-0 raw
// value (v0) falls out of the broadcast for free.
// ---------------------------------------------------------------------------
__device__ __forceinline__ float wave_sum(float v) {
#pragma unroll
    for (int off = 32; off > 0; off >>= 1) v += __shfl_xor(v, off, 64);
    return v;
}

#define ET_INIT(v, base)                            \
    v.x = __expf(trans[(base + 0) * NLAB + j]);     \
    v.y = __expf(trans[(base + 1) * NLAB + j]);     \
    v.z = __expf(trans[(base + 2) * NLAB + j]);     \
    v.w = __expf(trans[(base + 3) * NLAB + j]);

// broadcast lane i of the raw e-vector (ue) to all lanes
#define RLF(i) __uint_as_float(__builtin_amdgcn_readlane(__float_as_uint(ue), (i)))

__global__ __launch_bounds__(64) __attribute__((amdgpu_waves_per_eu(1, 1)))
void crf_kernel(
    const float* __restrict__ logits,
    const int* __restrict__ labels,
    const void* __restrict__ maskp,
    const float* __restrict__ startT,
    const float* __restrict__ endT,
    const float* __restrict__ trans,
    float* __restrict__ llh) {
    const int b = blockIdx.x;
    const int lane = threadIdx.x;

    // --- mask length (contiguous valid prefix) ---
    const int probe = ((const int*)maskp)[0];
    int len = 0;
    if (probe == 1) {
        const int* mk = (const int*)maskp + b * TLEN;
#pragma unroll
        for (int it = 0; it < 8; ++it)
            len += (int)__popcll(__ballot(mk[lane + it * 64] != 0));
    } else if (probe == 0x01010101) {
        const unsigned char* mk = (const unsigned char*)maskp + b * TLEN;
#pragma unroll
        for (int it = 0; it < 8; ++it)
            len += (int)__popcll(__ballot(mk[lane + it * 64] != 0));
    } else if (probe == 0x3F803F80) {
        const unsigned short* mk = (const unsigned short*)maskp + b * TLEN;
#pragma unroll
        for (int it = 0; it < 8; ++it)
            len += (int)__popcll(__ballot(mk[lane + it * 64] != 0));
    } else {
        const float* mk = (const float*)maskp + b * TLEN;
#pragma unroll
        for (int it = 0; it < 8; ++it)
            len += (int)__popcll(__ballot(mk[lane + it * 64] != 0.f));
    }

    const int j = lane;
    const int jc = (j < NLAB) ? j : (NLAB - 1);

    // et = exp(trans[:, j]) in 13 named float4 registers
    float4 et0  = {0.f,0.f,0.f,0.f}, et1  = {0.f,0.f,0.f,0.f};
    float4 et2  = {0.f,0.f,0.f,0.f}, et3  = {0.f,0.f,0.f,0.f};
    float4 et4  = {0.f,0.f,0.f,0.f}, et5  = {0.f,0.f,0.f,0.f};
    float4 et6  = {0.f,0.f,0.f,0.f}, et7  = {0.f,0.f,0.f,0.f};
    float4 et8  = {0.f,0.f,0.f,0.f}, et9  = {0.f,0.f,0.f,0.f};
    float4 et10 = {0.f,0.f,0.f,0.f}, et11 = {0.f,0.f,0.f,0.f};
    float4 et12 = {0.f,0.f,0.f,0.f};
    if (j < NLAB) {
        ET_INIT(et0,  0)  ET_INIT(et1,  4)  ET_INIT(et2,  8)
        ET_INIT(et3,  12) ET_INIT(et4,  16) ET_INIT(et5,  20)
        ET_INIT(et6,  24) ET_INIT(et7,  28) ET_INIT(et8,  32)
        ET_INIT(et9,  36) ET_INIT(et10, 40) ET_INIT(et11, 44)
        et12.x = __expf(trans[48 * NLAB + j]);
        et12.y = __expf(trans[49 * NLAB + j]);
    }

    const float* em = logits + (size_t)b * TLEN * NLAB;

    float a0v = (j < NLAB) ? (startT[j] + em[j]) : 0.f;
    const float Abc = __shfl(a0v, 0, 64);
    // ue = raw (un-normalized) e-vector value of this lane; lane 0 == 1.0
    float ue = (j < NLAB) ? __expf(a0v - Abc) : 0.f;
    float A = Abc;

    // 4-deep emission pipeline: named scalars, rotated by assignment.
    float q0 = em[1 * NLAB + jc];
    float q1 = em[2 * NLAB + jc];
    float q2 = em[3 * NLAB + jc];
    float q3 = em[4 * NLAB + jc];
    float pcur = __expf(q0);
    q0 = q1; q1 = q2; q2 = q3; q3 = em[5 * NLAB + jc];

    for (int t = 1; t < len; ++t) {
        int tf = t + 5; tf = (tf < len) ? tf : (len - 1);
        const float newem = em[tf * NLAB + jc];      // issued, used 4 iters later
        const float pnext = __expf(q0);              // off-chain

        const float b0 = RLF(0);                     // lane-0 raw value (free)
        const float rv = __builtin_amdgcn_rcpf(b0);  // off-chain vs dot
        A += __logf(b0);                             // off-chain
        const float pr = pcur * rv;                  // off-chain

        float c0 = 0.f, c1 = 0.f, c2 = 0.f, c3 = 0.f;
        float c4 = 0.f, c5 = 0.f, c6 = 0.f, c7 = 0.f;
        c0 = fmaf(b0,      et0.x,  c0);
        c1 = fmaf(RLF(1),  et0.y,  c1);
        c2 = fmaf(RLF(2),  et0.z,  c2);
        c3 = fmaf(RLF(3),  et0.w,  c3);
        c4 = fmaf(RLF(4),  et1.x,  c4);
        c5 = fmaf(RLF(5),  et1.y,  c5);
        c6 = fmaf(RLF(6),  et1.z,  c6);
        c7 = fmaf(RLF(7),  et1.w,  c7);
        c0 = fmaf(RLF(8),  et2.x,  c0);
        c1 = fmaf(RLF(9),  et2.y,  c1);
        c2 = fmaf(RLF(10), et2.z,  c2);
        c3 = fmaf(RLF(11), et2.w,  c3);
        c4 = fmaf(RLF(12), et3.x,  c4);
        c5 = fmaf(RLF(13), et3.y,  c5);
        c6 = fmaf(RLF(14), et3.z,  c6);
        c7 = fmaf(RLF(15), et3.w,  c7);
        c0 = fmaf(RLF(16), et4.x,  c0);
        c1 = fmaf(RLF(17), et4.y,  c1);
        c2 = fmaf(RLF(18), et4.z,  c2);
        c3 = fmaf(RLF(19), et4.w,  c3);
        c4 = fmaf(RLF(20), et5.x,  c4);
        c5 = fmaf(RLF(21), et5.y,  c5);
        c6 = fmaf(RLF(22), et5.z,  c6);
        c7 = fmaf(RLF(23), et5.w,  c7);
        c0 = fmaf(RLF(24), et6.x,  c0);
        c1 = fmaf(RLF(25), et6.y,  c1);
        c2 = fmaf(RLF(26), et6.z,  c2);
        c3 = fmaf(RLF(27), et6.w,  c3);
        c4 = fmaf(RLF(28), et7.x,  c4);
        c5 = fmaf(RLF(29), et7.y,  c5);
        c6 = fmaf(RLF(30), et7.z,  c6);
        c7 = fmaf(RLF(31), et7.w,  c7);
        c0 = fmaf(RLF(32), et8.x,  c0);
        c1 = fmaf(RLF(33), et8.y,  c1);
        c2 = fmaf(RLF(34), et8.z,  c2);
        c3 = fmaf(RLF(35), et8.w,  c3);
        c4 = fmaf(RLF(36), et9.x,  c4);
        c5 = fmaf(RLF(37), et9.y,  c5);
        c6 = fmaf(RLF(38), et9.z,  c6);
        c7 = fmaf(RLF(39), et9.w,  c7);
        c0 = fmaf(RLF(40), et10.x, c0);
        c1 = fmaf(RLF(41), et10.y, c1);
        c2 = fmaf(RLF(42), et10.z, c2);
        c3 = fmaf(RLF(43), et10.w, c3);
        c4 = fmaf(RLF(44), et11.x, c4);
        c5 = fmaf(RLF(45), et11.y, c5);
        c6 = fmaf(RLF(46), et11.z, c6);
        c7 = fmaf(RLF(47), et11.w, c7);
        c0 = fmaf(RLF(48), et12.x, c0);
        c1 = fmaf(RLF(49), et12.y, c1);

        const float s = ((c0 + c1) + (c2 + c3)) + ((c4 + c5) + (c6 + c7));
        ue = s * pr;                                 // raw (un-normalized)

        pcur = pnext; q0 = q1; q1 = q2; q2 = q3; q3 = newem;
    }

    // den = A + log( sum_j v_j * exp(end_j) )   [alpha_j = A + log v_j]
    const float wv = (j < NLAB) ? (ue * __expf(endT[j])) : 0.f;
    const float den = A + __logf(wave_sum(wv));

    // numerator: gold path (contiguous mask -> parallel over t)
    const int* tg = labels + b * TLEN;
    float num = 0.f;
#pragma unroll
    for (int it = 0; it < 8; ++it) {
        const int t = lane + it * 64;
        if (t < len) {
            const int tag = tg[t];
            num += em[t * NLAB + tag];
            if (t >= 1) num += trans[tg[t - 1] * NLAB + tag];
        }
    }
    num = wave_sum(num);
    if (lane == 0) {
        num += startT[tg[0]] + endT[tg[len - 1]];
        llh[b] = num - den;
    }
}

__global__ __launch_bounds__(64) void loss_kernel(const float* __restrict__ llh,
                                                  float* __restrict__ out0) {
    float v = llh[threadIdx.x];
    v = wave_sum(v);
    if (threadIdx.x == 0) out0[0] = -(v * (1.0f / BATCH));
}

extern "C" void kernel_launch(void* const* d_in, const int* in_sizes, int n_in,
                              void* d_out, int out_size, void* d_ws, size_t ws_size,
                              hipStream_t stream) {
    (void)in_sizes; (void)n_in; (void)out_size; (void)ws_size;
    const float* emb    = (const float*)d_in[0];
    const int*   labels = (const int*)d_in[1];
    const void*  mask   = d_in[2];
    const float* W      = (const float*)d_in[3];
    const float* bias   = (const float*)d_in[4];
    const float* startT = (const float*)d_in[5];
    const float* endT   = (const float*)d_in[6];
    const float* trans  = (const float*)d_in[7];

    float* out    = (float*)d_out;
    float* logits = out + 1;
    float* llh    = (float*)d_ws;
    unsigned short* Bt = (unsigned short*)((char*)d_ws + 512);  // 96 KiB bf16 W^T

    wprep_kernel<<<(64 * DIM + 255) / 256, 256, 0, stream>>>(W, Bt);
    gemm_kernel<<<(BATCH * TLEN) / 128, 256, 0, stream>>>(emb, Bt, bias, logits);
    crf_kernel<<<BATCH, 64, 0, stream>>>(logits, labels, mask, startT, endT, trans, llh);
    loss_kernel<<<1, 64, 0, stream>>>(llh, out);
}

// Round 2
// 311.084 us; speedup vs baseline: 1.0491x; 1.0055x over previous
//
#include <hip/hip_runtime.h>
#include <hip/hip_bf16.h>
#include <math.h>

#define BATCH 64
#define TLEN 512
#define DIM 768
#define NLAB 50

typedef __attribute__((ext_vector_type(8))) short short8;   // 8 bf16 (4 VGPRs)
typedef __attribute__((ext_vector_type(4))) float f32x4;    // MFMA acc

__device__ __forceinline__ unsigned short f2bf(float f) {
    unsigned int u = __float_as_uint(f);
    return (unsigned short)((u + 0x7FFFu + ((u >> 16) & 1u)) >> 16);
}

// ---------------------------------------------------------------------------
// prep: W fp32 [768 x 50] -> Bt bf16 [64 cols][768 k] (transposed, zero-pad)
// ---------------------------------------------------------------------------
__global__ __launch_bounds__(256) void wprep_kernel(const float* __restrict__ W,
                                                    unsigned short* __restrict__ Bt) {
    int idx = blockIdx.x * 256 + threadIdx.x;
    if (idx < 64 * DIM) {
        int c = idx / DIM;
        int k = idx - c * DIM;
        float v = (c < NLAB) ? W[k * NLAB + c] : 0.f;
        Bt[idx] = f2bf(v);
    }
}

// ---------------------------------------------------------------------------
// GEMM v2: streaming kernel was occupancy-starved (256 blocks / 256 CUs with
// waves_per_eu(1,1) -> 1 wave/SIMD; ~900cy HBM latency exposed).
// Now 512 thr / 8 waves per block (1 m-tile of 16 rows per wave), no
// waves-per-EU pin -> 2 waves/EU of pure streaming, same dbuf LDS pipeline.
// ---------------------------------------------------------------------------
#define AST 36
#define BSTC 40

__global__ __launch_bounds__(512)
void gemm_kernel(
    const float* __restrict__ A,              // [32768 x 768] fp32
    const unsigned short* __restrict__ Bt,    // [64 x 768] bf16 (W^T, padded)
    const float* __restrict__ bias,
    float* __restrict__ out)                  // [32768 x 50]
{
    __shared__ float As[2][128 * AST];
    __shared__ short Bs[2][64 * BSTC];

    const int tid = threadIdx.x;
    const int wave = tid >> 6;
    const int lane = tid & 63;
    const int m = lane & 15;
    const int q = lane >> 4;
    const int row0 = blockIdx.x * 128;

    // staging map: 512 threads cover 128 rows x 32 k per chunk
    const int r0s = tid >> 2;            // 0..127 (row)
    const int c0s = (tid & 3) * 8;       // k offset {0,8,16,24}, 2x float4 each
    const int bcol = tid >> 3;           // 0..63
    const int bkk = (tid & 7) * 4;       // 4 shorts per thread

    f32x4 acc0 = {0.f,0.f,0.f,0.f}, acc1 = {0.f,0.f,0.f,0.f};
    f32x4 acc2 = {0.f,0.f,0.f,0.f}, acc3 = {0.f,0.f,0.f,0.f};

    {
        *(float4*)&As[0][r0s * AST + c0s]     = *(const float4*)(A + (size_t)(row0 + r0s) * DIM + c0s);
        *(float4*)&As[0][r0s * AST + c0s + 4] = *(const float4*)(A + (size_t)(row0 + r0s) * DIM + c0s + 4);
        *(short4*)&Bs[0][bcol * BSTC + bkk]   = *(const short4*)(Bt + (size_t)bcol * DIM + bkk);
    }
    __syncthreads();

    int buf = 0;
    for (int ch = 0; ch < DIM / 32; ++ch) {
        const int k0n = (ch + 1) * 32;
        const bool havenext = (ch < DIM / 32 - 1);
        float4 pa0, pa1;
        short4 pb;
        if (havenext) {
            pa0 = *(const float4*)(A + (size_t)(row0 + r0s) * DIM + k0n + c0s);
            pa1 = *(const float4*)(A + (size_t)(row0 + r0s) * DIM + k0n + c0s + 4);
            pb  = *(const short4*)(Bt + (size_t)bcol * DIM + k0n + bkk);
        }

        const short8 bq0 = *(const short8*)&Bs[buf][( 0 + m) * BSTC + q * 8];
        const short8 bq1 = *(const short8*)&Bs[buf][(16 + m) * BSTC + q * 8];
        const short8 bq2 = *(const short8*)&Bs[buf][(32 + m) * BSTC + q * 8];
        const short8 bq3 = *(const short8*)&Bs[buf][(48 + m) * BSTC + q * 8];

        {
            const int rr = wave * 16 + m;
            const float4 xa = *(const float4*)&As[buf][rr * AST + q * 8];
            const float4 xb = *(const float4*)&As[buf][rr * AST + q * 8 + 4];
            short8 af;
            af[0] = (short)f2bf(xa.x); af[1] = (short)f2bf(xa.y);
            af[2] = (short)f2bf(xa.z); af[3] = (short)f2bf(xa.w);
            af[4] = (short)f2bf(xb.x); af[5] = (short)f2bf(xb.y);
            af[6] = (short)f2bf(xb.z); af[7] = (short)f2bf(xb.w);
            acc0 = __builtin_amdgcn_mfma_f32_16x16x32_bf16(af, bq0, acc0, 0, 0, 0);
            acc1 = __builtin_amdgcn_mfma_f32_16x16x32_bf16(af, bq1, acc1, 0, 0, 0);
            acc2 = __builtin_amdgcn_mfma_f32_16x16x32_bf16(af, bq2, acc2, 0, 0, 0);
            acc3 = __builtin_amdgcn_mfma_f32_16x16x32_bf16(af, bq3, acc3, 0, 0, 0);
        }

        if (havenext) {
            const int nb = buf ^ 1;
            *(float4*)&As[nb][r0s * AST + c0s]     = pa0;
            *(float4*)&As[nb][r0s * AST + c0s + 4] = pa1;
            *(short4*)&Bs[nb][bcol * BSTC + bkk]   = pb;
        }
        __syncthreads();
        buf ^= 1;
    }

    const int rb = row0 + wave * 16 + q * 4;
#pragma unroll
    for (int nt = 0; nt < 4; ++nt) {
        const f32x4 av = (nt == 0) ? acc0 : (nt == 1) ? acc1 : (nt == 2) ? acc2 : acc3;
        const int col = nt * 16 + m;
        if (col < NLAB) {
            const float bv = bias[col];
#pragma unroll
            for (int r = 0; r < 4; ++r)
                out[(size_t)(rb + r) * NLAB + col] = av[r] + bv;
        }
    }
}

// ---------------------------------------------------------------------------
// CRF v9: LDS-free recurrence (unchanged from R1; 141.5 us, ~668 cyc/step,
// latency-bound on readlane->fma chain. Next structural step: batched-MFMA
// scan. Kept as-is this round while gemm occupancy is fixed.)
// ---------------------------------------------------------------------------
__device__ __forceinline__ float wave_sum(float v) {
#pragma unroll
    for (int off = 32; off > 0; off >>= 1) v += __shfl_xor(v, off, 64);
    return v;
}

#define ET_INIT(v, base)                            \
    v.x = __expf(trans[(base + 0) * NLAB + j]);     \
    v.y = __expf(trans[(base + 1) * NLAB + j]);     \
    v.z = __expf(trans[(base + 2) * NLAB + j]);     \
    v.w = __expf(trans[(base + 3) * NLAB + j]);

// broadcast lane i of the raw e-vector (ue) to all lanes
#define RLF(i) __uint_as_float(__builtin_amdgcn_readlane(__float_as_uint(ue), (i)))

__global__ __launch_bounds__(64) __attribute__((amdgpu_waves_per_eu(1, 1)))
void crf_kernel(
    const float* __restrict__ logits,
    const int* __restrict__ labels,
    const void* __restrict__ maskp,
    const float* __restrict__ startT,
    const float* __restrict__ endT,
    const float* __restrict__ trans,
    float* __restrict__ llh) {
    const int b = blockIdx.x;
    const int lane = threadIdx.x;

    // --- mask length (contiguous valid prefix) ---
    const int probe = ((const int*)maskp)[0];
    int len = 0;
    if (probe == 1) {
        const int* mk = (const int*)maskp + b * TLEN;
#pragma unroll
        for (int it = 0; it < 8; ++it)
            len += (int)__popcll(__ballot(mk[lane + it * 64] != 0));
    } else if (probe == 0x01010101) {
        const unsigned char* mk = (const unsigned char*)maskp + b * TLEN;
#pragma unroll
        for (int it = 0; it < 8; ++it)
            len += (int)__popcll(__ballot(mk[lane + it * 64] != 0));
    } else if (probe == 0x3F803F80) {
        const unsigned short* mk = (const unsigned short*)maskp + b * TLEN;
#pragma unroll
        for (int it = 0; it < 8; ++it)
            len += (int)__popcll(__ballot(mk[lane + it * 64] != 0));
    } else {
        const float* mk = (const float*)maskp + b * TLEN;
#pragma unroll
        for (int it = 0; it < 8; ++it)
            len += (int)__popcll(__ballot(mk[lane + it * 64] != 0.f));
    }

    const int j = lane;
    const int jc = (j < NLAB) ? j : (NLAB - 1);

    // et = exp(trans[:, j]) in 13 named float4 registers
    float4 et0  = {0.f,0.f,0.f,0.f}, et1  = {0.f,0.f,0.f,0.f};
    float4 et2  = {0.f,0.f,0.f,0.f}, et3  = {0.f,0.f,0.f,0.f};
    float4 et4  = {0.f,0.f,0.f,0.f}, et5  = {0.f,0.f,0.f,0.f};
    float4 et6  = {0.f,0.f,0.f,0.f}, et7  = {0.f,0.f,0.f,0.f};
    float4 et8  = {0.f,0.f,0.f,0.f}, et9  = {0.f,0.f,0.f,0.f};
    float4 et10 = {0.f,0.f,0.f,0.f}, et11 = {0.f,0.f,0.f,0.f};
    float4 et12 = {0.f,0.f,0.f,0.f};
    if (j < NLAB) {
        ET_INIT(et0,  0)  ET_INIT(et1,  4)  ET_INIT(et2,  8)
        ET_INIT(et3,  12) ET_INIT(et4,  16) ET_INIT(et5,  20)
        ET_INIT(et6,  24) ET_INIT(et7,  28) ET_INIT(et8,  32)
        ET_INIT(et9,  36) ET_INIT(et10, 40) ET_INIT(et11, 44)
        et12.x = __expf(trans[48 * NLAB + j]);
        et12.y = __expf(trans[49 * NLAB + j]);
    }

    const float* em = logits + (size_t)b * TLEN * NLAB;

    float a0v = (j < NLAB) ? (startT[j] + em[j]) : 0.f;
    const float Abc = __shfl(a0v, 0, 64);
    // ue = raw (un-normalized) e-vector value of this lane; lane 0 == 1.0
    float ue = (j < NLAB) ? __expf(a0v - Abc) : 0.f;
    float A = Abc;

    // 4-deep emission pipeline: named scalars, rotated by assignment.
    float q0 = em[1 * NLAB + jc];
    float q1 = em[2 * NLAB + jc];
    float q2 = em[3 * NLAB + jc];
    float q3 = em[4 * NLAB + jc];
    float pcur = __expf(q0);
    q0 = q1; q1 = q2; q2 = q3; q3 = em[5 * NLAB + jc];

    for (int t = 1; t < len; ++t) {
        int tf = t + 5; tf = (tf < len) ? tf : (len - 1);
        const float newem = em[tf * NLAB + jc];      // issued, used 4 iters later
        const float pnext = __expf(q0);              // off-chain

        const float b0 = RLF(0);                     // lane-0 raw value (free)
        const float rv = __builtin_amdgcn_rcpf(b0);  // off-chain vs dot
        A += __logf(b0);                             // off-chain
        const float pr = pcur * rv;                  // off-chain

        float c0 = 0.f, c1 = 0.f, c2 = 0.f, c3 = 0.f;
        float c4 = 0.f, c5 = 0.f, c6 = 0.f, c7 = 0.f;
        c0 = fmaf(b0,      et0.x,  c0);
        c1 = fmaf(RLF(1),  et0.y,  c1);
        c2 = fmaf(RLF(2),  et0.z,  c2);
        c3 = fmaf(RLF(3),  et0.w,  c3);
        c4 = fmaf(RLF(4),  et1.x,  c4);
        c5 = fmaf(RLF(5),  et1.y,  c5);
        c6 = fmaf(RLF(6),  et1.z,  c6);
        c7 = fmaf(RLF(7),  et1.w,  c7);
        c0 = fmaf(RLF(8),  et2.x,  c0);
        c1 = fmaf(RLF(9),  et2.y,  c1);
        c2 = fmaf(RLF(10), et2.z,  c2);
        c3 = fmaf(RLF(11), et2.w,  c3);
        c4 = fmaf(RLF(12), et3.x,  c4);
        c5 = fmaf(RLF(13), et3.y,  c5);
        c6 = fmaf(RLF(14), et3.z,  c6);
        c7 = fmaf(RLF(15), et3.w,  c7);
        c0 = fmaf(RLF(16), et4.x,  c0);
        c1 = fmaf(RLF(17), et4.y,  c1);
        c2 = fmaf(RLF(18), et4.z,  c2);
        c3 = fmaf(RLF(19), et4.w,  c3);
        c4 = fmaf(RLF(20), et5.x,  c4);
        c5 = fmaf(RLF(21), et5.y,  c5);
        c6 = fmaf(RLF(22), et5.z,  c6);
        c7 = fmaf(RLF(23), et5.w,  c7);
        c0 = fmaf(RLF(24), et6.x,  c0);
        c1 = fmaf(RLF(25), et6.y,  c1);
        c2 = fmaf(RLF(26), et6.z,  c2);
        c3 = fmaf(RLF(27), et6.w,  c3);
        c4 = fmaf(RLF(28), et7.x,  c4);
        c5 = fmaf(RLF(29), et7.y,  c5);
        c6 = fmaf(RLF(30), et7.z,  c6);
        c7 = fmaf(RLF(31), et7.w,  c7);
        c0 = fmaf(RLF(32), et8.x,  c0);
        c1 = fmaf(RLF(33), et8.y,  c1);
        c2 = fmaf(RLF(34), et8.z,  c2);
        c3 = fmaf(RLF(35), et8.w,  c3);
        c4 = fmaf(RLF(36), et9.x,  c4);
        c5 = fmaf(RLF(37), et9.y,  c5);
        c6 = fmaf(RLF(38), et9.z,  c6);
        c7 = fmaf(RLF(39), et9.w,  c7);
        c0 = fmaf(RLF(40), et10.x, c0);
        c1 = fmaf(RLF(41), et10.y, c1);
        c2 = fmaf(RLF(42), et10.z, c2);
        c3 = fmaf(RLF(43), et10.w, c3);
        c4 = fmaf(RLF(44), et11.x, c4);
        c5 = fmaf(RLF(45), et11.y, c5);
        c6 = fmaf(RLF(46), et11.z, c6);
        c7 = fmaf(RLF(47), et11.w, c7);
        c0 = fmaf(RLF(48), et12.x, c0);
        c1 = fmaf(RLF(49), et12.y, c1);

        const float s = ((c0 + c1) + (c2 + c3)) + ((c4 + c5) + (c6 + c7));
        ue = s * pr;                                 // raw (un-normalized)

        pcur = pnext; q0 = q1; q1 = q2; q2 = q3; q3 = newem;
    }

    // den = A + log( sum_j v_j * exp(end_j) )   [alpha_j = A + log v_j]
    const float wv = (j < NLAB) ? (ue * __expf(endT[j])) : 0.f;
    const float den = A + __logf(wave_sum(wv));

    // numerator: gold path (contiguous mask -> parallel over t)
    const int* tg = labels + b * TLEN;
    float num = 0.f;
#pragma unroll
    for (int it = 0; it < 8; ++it) {
        const int t = lane + it * 64;
        if (t < len) {
            const int tag = tg[t];
            num += em[t * NLAB + tag];
            if (t >= 1) num += trans[tg[t - 1] * NLAB + tag];
        }
    }
    num = wave_sum(num);
    if (lane == 0) {
        num += startT[tg[0]] + endT[tg[len - 1]];
        llh[b] = num - den;
    }
}

__global__ __launch_bounds__(64) void loss_kernel(const float* __restrict__ llh,
                                                  float* __restrict__ out0) {
    float v = llh[threadIdx.x];
    v = wave_sum(v);
    if (threadIdx.x == 0) out0[0] = -(v * (1.0f / BATCH));
}

extern "C" void kernel_launch(void* const* d_in, const int* in_sizes, int n_in,
                              void* d_out, int out_size, void* d_ws, size_t ws_size,
                              hipStream_t stream) {
    (void)in_sizes; (void)n_in; (void)out_size; (void)ws_size;
    const float* emb    = (const float*)d_in[0];
    const int*   labels = (const int*)d_in[1];
    const void*  mask   = d_in[2];
    const float* W      = (const float*)d_in[3];
    const float* bias   = (const float*)d_in[4];
    const float* startT = (const float*)d_in[5];
    const float* endT   = (const float*)d_in[6];
    const float* trans  = (const float*)d_in[7];

    float* out    = (float*)d_out;
    float* logits = out + 1;
    float* llh    = (float*)d_ws;
    unsigned short* Bt = (unsigned short*)((char*)d_ws + 512);  // 96 KiB bf16 W^T

    wprep_kernel<<<(64 * DIM + 255) / 256, 256, 0, stream>>>(W, Bt);
    gemm_kernel<<<(BATCH * TLEN) / 128, 512, 0, stream>>>(emb, Bt, bias, logits);
    crf_kernel<<<BATCH, 64, 0, stream>>>(logits, labels, mask, startT, endT, trans, llh);
    loss_kernel<<<1, 64, 0, stream>>>(llh, out);
}